// Round 1
// 323.586 us; speedup vs baseline: 1.0019x; 1.0019x over previous
//
#include <hip/hip_runtime.h>
#include <math.h>

// Kernel A: segment boundaries via binary search (ray_id is sorted).
// seg_start[r] = first index i with ray_id[i] >= r, for r in [0, N].
__global__ void seg_starts_kernel(const int* __restrict__ ray_id, int M, int N,
                                  int* __restrict__ seg_start) {
    int r = blockIdx.x * blockDim.x + threadIdx.x;
    if (r > N) return;
    int lo = 0, hi = M;
    while (lo < hi) {
        int mid = (lo + hi) >> 1;
        if (ray_id[mid] < r) lo = mid + 1;
        else hi = mid;
    }
    seg_start[r] = lo;
}

// Kernel B: ONE ray per 64-lane wave, 64-sample chunks.
// Stats of this input (shift=-1, interval=0.5, d~N(0,1)): E[-log t] ~= 0.20
// per sample -> the T<1e-3 cutoff (sum 6.9) is reached after ~34 samples, so
// a single 64-sample chunk terminates ~99.6% of rays: exactly ONE exposed
// load-latency per ray (vs ~3 serial 32-sample chunks + ray-pairing
// imbalance in the previous 2-rays/wave version).
// t_i = (1+exp(d+shift))^(-interval) == reference (1-alpha) exactly.
// weights_i = T_i - T_{i+1}. Early exit at T < 1e-3: dropped tail + bg
// perturbation bound the output error by ~2e-3 (<< 1.78e-2 threshold).
__launch_bounds__(256, 8)
__global__ void composite_kernel(const float* __restrict__ density,
                                 const float* __restrict__ rgb,
                                 const float* __restrict__ bg,
                                 const float* __restrict__ shift_p,
                                 const float* __restrict__ interval_p,
                                 const int* __restrict__ seg_start,
                                 float* __restrict__ out, int N, int M) {
    const int wave = threadIdx.x >> 6;
    const int lane = threadIdx.x & 63;
    const int ray  = blockIdx.x * (blockDim.x >> 6) + wave;

    const float shift = *shift_p;
    const float nI = -(*interval_p);

    int s = 0, e = 0;
    if (ray < N) { s = seg_start[ray]; e = seg_start[ray + 1]; }

    float T = 1.0f;                 // running transmittance (wave-uniform)
    float ar = 0.f, ag = 0.f, ab = 0.f;
    int  base   = s;
    bool active = (base < e);       // wave-uniform: loop has no divergence

    while (active) {
        int i = base + lane;
        bool valid = (i < e);
        int ic = (i < M - 1) ? i : (M - 1);     // in-bounds, coalesced
        float d  = density[ic];
        float cr = rgb[3 * ic + 0];
        float cg = rgb[3 * ic + 1];
        float cb = rgb[3 * ic + 2];
        // branch-free transmittance; invalid lanes forced to identity t=1
        float t = exp2f(nI * __log2f(1.0f + __expf(d + shift)));
        t = valid ? t : 1.0f;

        // inclusive product scan across the full 64-lane wave
        float p = t;
        #pragma unroll
        for (int off = 1; off < 64; off <<= 1) {
            float o = __shfl_up(p, off, 64);
            p *= (lane >= off) ? o : 1.0f;
        }
        float excl = __shfl_up(p, 1, 64);
        if (lane == 0) excl = 1.0f;
        float wgt = T * (excl - p);   // = T_i - T_{i+1}; 0 on invalid lanes
        ar += wgt * cr;
        ag += wgt * cg;
        ab += wgt * cb;

        float chunk = __shfl(p, 63, 64);   // wave-uniform chunk product
        T *= chunk;
        base += 64;
        active = (base < e) && (T >= 1e-3f);
    }

    // rgb reduction across the wave
    #pragma unroll
    for (int off = 32; off > 0; off >>= 1) {
        ar += __shfl_xor(ar, off, 64);
        ag += __shfl_xor(ag, off, 64);
        ab += __shfl_xor(ab, off, 64);
    }

    if (lane == 0 && ray < N) {
        out[3 * ray + 0] = ar + T * bg[0];
        out[3 * ray + 1] = ag + T * bg[1];
        out[3 * ray + 2] = ab + T * bg[2];
    }
}

extern "C" void kernel_launch(void* const* d_in, const int* in_sizes, int n_in,
                              void* d_out, int out_size, void* d_ws, size_t ws_size,
                              hipStream_t stream) {
    const float* density  = (const float*)d_in[0];
    const float* rgb      = (const float*)d_in[1];
    const float* bg       = (const float*)d_in[2];
    const float* shift    = (const float*)d_in[3];
    const float* interval = (const float*)d_in[4];
    const int*   ray_id   = (const int*)d_in[5];

    const int M = in_sizes[0];       // samples
    const int N = out_size / 3;      // rays

    int* seg_start = (int*)d_ws;     // N+1 ints

    {
        int threads = 256;
        int blocks = (N + 1 + threads - 1) / threads;
        seg_starts_kernel<<<blocks, threads, 0, stream>>>(ray_id, M, N, seg_start);
    }
    {
        // 4 waves/block, 1 ray per wave -> 4 rays per block
        int raysPerBlock = 4;
        int blocks = (N + raysPerBlock - 1) / raysPerBlock;
        composite_kernel<<<blocks, 256, 0, stream>>>(density, rgb, bg, shift,
                                                     interval, seg_start,
                                                     (float*)d_out, N, M);
    }
}